// Round 7
// baseline (4480.595 us; speedup 1.0000x reference)
//
#include <hip/hip_runtime.h>
#include <math.h>

// ======================= DIAGNOSTIC ROUND =======================
// R2 structure (measured best, 39.6us) kept for correctness; the three
// interesting kernels run REP-looped so each dispatch is >1.2ms and
// appears in rocprof's top-5 with per-kernel counters.
// ================================================================

constexpr int Bn = 1024;
constexpr int S  = 512;
constexpr int H  = 768;
constexpr int D1 = 128;
constexpr int HV = H / 4;     // 192 float4 per feature row

constexpr int POOL_REPS  = 64;
constexpr int HEADA_REPS = 128;
constexpr int HEADB_REPS = 96;

constexpr int NSUB = 32;               // head_b geometry (R6-style)
constexpr int DSUB = (2 * H) / NSUB;   // 48

// ws layout (floats):
//   cls [Bn][768]       3 MB
//   gp  [2][Bn][768]    6 MB
//   P   [4][Bn][D1]     2 MB   (real, consumed by finalize)
//   P2  [Bn][NSUB][D1] 16 MB   (scratch, head_b profiling only)

__device__ __forceinline__ int opaque_zero() {
  int zero;
  asm volatile("v_mov_b32 %0, 0" : "=v"(zero));
  return zero;
}

// Kernel 1: R2-exact pool + rotating-window reps (last rep = true span).
__global__ __launch_bounds__(192) void pool_partial(
    const float* __restrict__ feat, const int* __restrict__ start,
    const int* __restrict__ endp, float* __restrict__ cls,
    float* __restrict__ gp) {
  const int b = blockIdx.x >> 1;
  const int p = blockIdx.x & 1;
  const int t = threadIdx.x;
  const int zero = opaque_zero();
  const float4* base =
      reinterpret_cast<const float4*>(feat) + (size_t)b * (S * HV) + zero;

  if (p == 0) {
    reinterpret_cast<float4*>(cls)[(size_t)b * HV + t] = base[t];  // CLS row
  }

  const int s0 = start[b];
  const int s1 = endp[b];
  const int len = s1 - s0;
  const float inv = 1.0f / (float)len;

  for (int rep = 0; rep < POOL_REPS; ++rep) {
    // rotate the window so reps don't go L3-warm; final rep is the real span
    const int x = (rep == POOL_REPS - 1) ? s0 : (1 + ((s0 - 1) + rep * 37) % 199);
    const int e = x + len;
    float4 a0{0,0,0,0}, a1{0,0,0,0}, a2{0,0,0,0}, a3{0,0,0,0};
    int s = x + p;
    for (; s + 6 < e; s += 8) {
      float4 v0 = base[(size_t)(s    ) * HV + t];
      float4 v1 = base[(size_t)(s + 2) * HV + t];
      float4 v2 = base[(size_t)(s + 4) * HV + t];
      float4 v3 = base[(size_t)(s + 6) * HV + t];
      a0.x += v0.x; a0.y += v0.y; a0.z += v0.z; a0.w += v0.w;
      a1.x += v1.x; a1.y += v1.y; a1.z += v1.z; a1.w += v1.w;
      a2.x += v2.x; a2.y += v2.y; a2.z += v2.z; a2.w += v2.w;
      a3.x += v3.x; a3.y += v3.y; a3.z += v3.z; a3.w += v3.w;
    }
    for (; s < e; s += 2) {
      float4 v = base[(size_t)s * HV + t];
      a0.x += v.x; a0.y += v.y; a0.z += v.z; a0.w += v.w;
    }
    float4 r;
    r.x = ((a0.x + a1.x) + (a2.x + a3.x)) * inv;
    r.y = ((a0.y + a1.y) + (a2.y + a3.y)) * inv;
    r.z = ((a0.z + a1.z) + (a2.z + a3.z)) * inv;
    r.w = ((a0.w + a1.w) + (a2.w + a3.w)) * inv;
    asm volatile("" :: "v"(r.x), "v"(r.y), "v"(r.z), "v"(r.w));  // keep live
    reinterpret_cast<float4*>(gp)[((size_t)p * Bn + b) * HV + t] = r;
  }
}

// Kernel 2a: R2-exact head, rep-looped. Writes the REAL P.
__global__ __launch_bounds__(256) void head_a(
    const float* __restrict__ cls, const float* __restrict__ gp,
    const float* __restrict__ W1, float* __restrict__ P) {
  __shared__ float g[4][384];
  __shared__ float part[2][4][D1];

  const int t = threadIdx.x;
  const int c = blockIdx.x & 3;
  const int eg = blockIdx.x >> 2;
  const int e0 = eg * 4;
  const int dglob0 = c * 384;
  const int zero = opaque_zero();
  const float* clsz = cls + zero;
  const float* gpz  = gp + zero;
  const float* W1z  = W1 + zero;

  for (int rep = 0; rep < HEADA_REPS; ++rep) {
    for (int i = t; i < 384; i += 256) {
      const int e = i / 96;
      const int j = i % 96;
      const int d = dglob0 + j * 4;
      float4 v;
      if (d < H) {
        v = *reinterpret_cast<const float4*>(clsz + (size_t)(e0 + e) * H + d);
      } else {
        const int dd = d - H;
        float4 u0 = *reinterpret_cast<const float4*>(
            gpz + (size_t)(e0 + e) * H + dd);
        float4 u1 = *reinterpret_cast<const float4*>(
            gpz + (size_t)Bn * H + (size_t)(e0 + e) * H + dd);
        v.x = u0.x + u1.x; v.y = u0.y + u1.y;
        v.z = u0.z + u1.z; v.w = u0.w + u1.w;
      }
      reinterpret_cast<float4*>(&g[e][0])[j] = v;
    }
    __syncthreads();

    const int k = t & (D1 - 1);
    const int sub = t >> 7;
    const int gofs = sub * 192;
    const float* Wc = W1z + (size_t)(dglob0 + gofs) * D1 + k;

    float a0 = 0.f, a1 = 0.f, a2 = 0.f, a3 = 0.f;
    #pragma unroll 4
    for (int d = 0; d < 192; d += 4) {
      float w0 = Wc[(size_t)(d + 0) * D1];
      float w1 = Wc[(size_t)(d + 1) * D1];
      float w2 = Wc[(size_t)(d + 2) * D1];
      float w3 = Wc[(size_t)(d + 3) * D1];
      float4 g0 = *reinterpret_cast<const float4*>(&g[0][gofs + d]);
      float4 g1 = *reinterpret_cast<const float4*>(&g[1][gofs + d]);
      float4 g2 = *reinterpret_cast<const float4*>(&g[2][gofs + d]);
      float4 g3 = *reinterpret_cast<const float4*>(&g[3][gofs + d]);
      a0 += g0.x * w0 + g0.y * w1 + g0.z * w2 + g0.w * w3;
      a1 += g1.x * w0 + g1.y * w1 + g1.z * w2 + g1.w * w3;
      a2 += g2.x * w0 + g2.y * w1 + g2.z * w2 + g2.w * w3;
      a3 += g3.x * w0 + g3.y * w1 + g3.z * w2 + g3.w * w3;
    }
    asm volatile("" :: "v"(a0), "v"(a1), "v"(a2), "v"(a3));  // keep live
    part[sub][0][k] = a0;
    part[sub][1][k] = a1;
    part[sub][2][k] = a2;
    part[sub][3][k] = a3;
    __syncthreads();

    if (t < D1) {
      #pragma unroll
      for (int e = 0; e < 4; ++e) {
        P[((size_t)c * Bn + (e0 + e)) * D1 + t] = part[0][e][t] + part[1][e][t];
      }
    }
    __syncthreads();
  }
}

// Kernel 2b: R6-style head (the +21us regressor), rep-looped into scratch P2.
// Profiling only; result unused.
__global__ __launch_bounds__(128) void head_b(
    const float* __restrict__ cls, const float* __restrict__ gp,
    const float* __restrict__ W1, float* __restrict__ P2) {
  const int t   = threadIdx.x;
  const int l   = t & 63;
  const int w   = t >> 6;
  const int eg  = blockIdx.x >> 4;
  const int dp  = blockIdx.x & 15;
  const int sub = dp * 2 + w;
  const int d0  = sub * DSUB;
  const int kq  = l & 31;
  const int eh  = l >> 5;
  const int ebase = eg * 8 + eh * 4;
  const int zero = opaque_zero();

  const float4* Wv =
      reinterpret_cast<const float4*>(W1 + (size_t)d0 * D1 + zero) + kq;

  for (int rep = 0; rep < HEADB_REPS; ++rep) {
    float4 acc[4];
    #pragma unroll
    for (int i = 0; i < 4; ++i) acc[i] = make_float4(0.f, 0.f, 0.f, 0.f);

    const bool isCls = (d0 < H);
    const int dd0 = isCls ? d0 : d0 - H;
    const float* gbase = (isCls ? cls : gp) + zero + dd0;
    const size_t off = (size_t)Bn * H;

    #pragma unroll 4
    for (int grp = 0; grp < DSUB / 4; ++grp) {
      const int dd = grp * 4;
      float4 w0 = Wv[(size_t)(dd + 0) * 32];
      float4 w1 = Wv[(size_t)(dd + 1) * 32];
      float4 w2 = Wv[(size_t)(dd + 2) * 32];
      float4 w3 = Wv[(size_t)(dd + 3) * 32];
      #pragma unroll
      for (int i = 0; i < 4; ++i) {
        const float* ga = gbase + (size_t)(ebase + i) * H;
        float4 gv = reinterpret_cast<const float4*>(ga)[grp];
        if (!isCls) {
          float4 u = reinterpret_cast<const float4*>(ga + off)[grp];
          gv.x += u.x; gv.y += u.y; gv.z += u.z; gv.w += u.w;
        }
        acc[i].x += gv.x * w0.x + gv.y * w1.x + gv.z * w2.x + gv.w * w3.x;
        acc[i].y += gv.x * w0.y + gv.y * w1.y + gv.z * w2.y + gv.w * w3.y;
        acc[i].z += gv.x * w0.z + gv.y * w1.z + gv.z * w2.z + gv.w * w3.z;
        acc[i].w += gv.x * w0.w + gv.y * w1.w + gv.z * w2.w + gv.w * w3.w;
      }
    }
    asm volatile("" :: "v"(acc[0].x), "v"(acc[1].x), "v"(acc[2].x),
                       "v"(acc[3].x), "v"(acc[0].w), "v"(acc[1].w),
                       "v"(acc[2].w), "v"(acc[3].w));
    #pragma unroll
    for (int i = 0; i < 4; ++i) {
      reinterpret_cast<float4*>(
          P2 + ((size_t)(ebase + i) * NSUB + sub) * D1)[kq] = acc[i];
    }
  }
}

// Kernel 3: R2-exact finalize (reads real P from head_a).
__global__ __launch_bounds__(256) void finalize(
    const float* __restrict__ P, const float* __restrict__ b1,
    const float* __restrict__ W2, const float* __restrict__ b2,
    float* __restrict__ out) {
  const int t = threadIdx.x;
  const int w = t >> 6, l = t & 63;
  const int e = blockIdx.x * 4 + w;
  const int k0 = l, k1 = l + 64;
  float h0 = b1[k0], h1 = b1[k1];
  #pragma unroll
  for (int c = 0; c < 4; ++c) {
    h0 += P[((size_t)c * Bn + e) * D1 + k0];
    h1 += P[((size_t)c * Bn + e) * D1 + k1];
  }
  h0 = fmaxf(h0, 0.f); h1 = fmaxf(h1, 0.f);
  float v = h0 * W2[k0] + h1 * W2[k1];
  #pragma unroll
  for (int off = 32; off > 0; off >>= 1) v += __shfl_down(v, off);
  if (l == 0) out[e] = 1.0f / (1.0f + expf(-(v + b2[0])));
}

extern "C" void kernel_launch(void* const* d_in, const int* in_sizes, int n_in,
                              void* d_out, int out_size, void* d_ws, size_t ws_size,
                              hipStream_t stream) {
  const float* feat = (const float*)d_in[0];
  const int* start  = (const int*)d_in[1];
  const int* endp   = (const int*)d_in[2];
  const float* W1   = (const float*)d_in[3];
  const float* b1   = (const float*)d_in[4];
  const float* W2   = (const float*)d_in[5];
  const float* b2   = (const float*)d_in[6];
  float* out = (float*)d_out;

  float* wsf = (float*)d_ws;
  float* cls = wsf;                            // [Bn][768]
  float* gp  = cls + (size_t)Bn * H;           // [2][Bn][768]
  float* P   = gp + (size_t)2 * Bn * H;        // [4][Bn][D1]
  float* P2  = P + (size_t)4 * Bn * D1;        // [Bn][NSUB][D1] scratch

  hipLaunchKernelGGL(pool_partial, dim3(Bn * 2), dim3(192), 0, stream,
                     feat, start, endp, cls, gp);
  hipLaunchKernelGGL(head_a, dim3(Bn), dim3(256), 0, stream,
                     cls, gp, W1, P);
  hipLaunchKernelGGL(head_b, dim3((Bn / 8) * (NSUB / 2)), dim3(128), 0, stream,
                     cls, gp, W1, P2);
  hipLaunchKernelGGL(finalize, dim3(Bn / 4), dim3(256), 0, stream,
                     P, b1, W2, b2, out);
}

// Round 8
// 34.542 us; speedup vs baseline: 129.7144x; 129.7144x over previous
//
#include <hip/hip_runtime.h>
#include <math.h>

// Problem constants (from reference):
constexpr int Bn = 1024;
constexpr int S  = 512;
constexpr int H  = 768;
constexpr int D1 = 128;
constexpr int HV = H / 4;     // 192 float4 per feature row
constexpr int NH = 512;       // cls-head blocks fused into launch 1

// ws layout (floats):
//   gp [2][Bn][768]  — span-mean partials (even/odd rows), pre-scaled by 1/len
//   P  [4][Bn][D1]   — per-384-d-chunk partial h dots

// ---------------- shared head inner loop (R2-exact) ----------------
// g[4][384] staged in LDS; lane k of 128 owns output k; sub = which 192-d half.
// Per d: 1 coalesced W1 b32 load (L2-hit) + 1 LDS broadcast + FMA x4 examples.
__device__ __forceinline__ void head_inner(
    const float (*g)[384], float (*part)[4][D1], const float* __restrict__ W1,
    float* __restrict__ P, int dglob0, int c, int e0, int t) {
  const int k = t & (D1 - 1);
  const int sub = t >> 7;
  const int gofs = sub * 192;
  const float* Wc = W1 + (size_t)(dglob0 + gofs) * D1 + k;

  float a0 = 0.f, a1 = 0.f, a2 = 0.f, a3 = 0.f;
  #pragma unroll 4
  for (int d = 0; d < 192; d += 4) {
    float w0 = Wc[(size_t)(d + 0) * D1];
    float w1 = Wc[(size_t)(d + 1) * D1];
    float w2 = Wc[(size_t)(d + 2) * D1];
    float w3 = Wc[(size_t)(d + 3) * D1];
    float4 g0 = *reinterpret_cast<const float4*>(&g[0][gofs + d]);
    float4 g1 = *reinterpret_cast<const float4*>(&g[1][gofs + d]);
    float4 g2 = *reinterpret_cast<const float4*>(&g[2][gofs + d]);
    float4 g3 = *reinterpret_cast<const float4*>(&g[3][gofs + d]);
    a0 += g0.x * w0 + g0.y * w1 + g0.z * w2 + g0.w * w3;
    a1 += g1.x * w0 + g1.y * w1 + g1.z * w2 + g1.w * w3;
    a2 += g2.x * w0 + g2.y * w1 + g2.z * w2 + g2.w * w3;
    a3 += g3.x * w0 + g3.y * w1 + g3.z * w2 + g3.w * w3;
  }
  part[sub][0][k] = a0;
  part[sub][1][k] = a1;
  part[sub][2][k] = a2;
  part[sub][3][k] = a3;
  __syncthreads();

  if (t < D1) {
    #pragma unroll
    for (int e = 0; e < 4; ++e) {
      P[((size_t)c * Bn + (e0 + e)) * D1 + t] = part[0][e][t] + part[1][e][t];
    }
  }
}

// Launch 1: fat kernel. Blocks [0,NH) = CLS-half head (independent of pool,
// reads feat row 0 directly); blocks [NH, NH+2048) = R2-exact pool.
// Co-residency lets the head's VALU/L2 work hide under the pool's HBM stalls.
__global__ __launch_bounds__(256) void fused_pool_clshead(
    const float* __restrict__ feat, const int* __restrict__ start,
    const int* __restrict__ endp, float* __restrict__ gp,
    const float* __restrict__ W1, float* __restrict__ P) {
  __shared__ float g[4][384];        // 6 KB (head path only)
  __shared__ float part[2][4][D1];   // 4 KB

  const int t = threadIdx.x;

  if (blockIdx.x < NH) {
    // ---- CLS-half head: chunk c in {0,1}, 4 examples ----
    const int c = blockIdx.x & 1;
    const int e0 = (blockIdx.x >> 1) * 4;
    const int dglob0 = c * 384;

    for (int i = t; i < 384; i += 256) {
      const int e = i / 96;          // 96 float4 per example-chunk
      const int j = i % 96;
      float4 v = *reinterpret_cast<const float4*>(
          feat + (size_t)(e0 + e) * S * H + dglob0 + j * 4);
      reinterpret_cast<float4*>(&g[e][0])[j] = v;
    }
    __syncthreads();
    head_inner(g, part, W1, P, dglob0, c, e0, t);
    return;
  }

  // ---- pool: R2-exact span mean-pool (no cls write) ----
  if (t >= 192) return;              // wave 3 retires immediately
  const int bb = blockIdx.x - NH;
  const int b = bb >> 1;
  const int p = bb & 1;
  const float4* base = reinterpret_cast<const float4*>(feat) + (size_t)b * (S * HV);

  const int s0 = start[b];
  const int s1 = endp[b];
  float4 a0{0,0,0,0}, a1{0,0,0,0}, a2{0,0,0,0}, a3{0,0,0,0};
  int s = s0 + p;
  for (; s + 6 < s1; s += 8) {
    float4 v0 = base[(size_t)(s    ) * HV + t];
    float4 v1 = base[(size_t)(s + 2) * HV + t];
    float4 v2 = base[(size_t)(s + 4) * HV + t];
    float4 v3 = base[(size_t)(s + 6) * HV + t];
    a0.x += v0.x; a0.y += v0.y; a0.z += v0.z; a0.w += v0.w;
    a1.x += v1.x; a1.y += v1.y; a1.z += v1.z; a1.w += v1.w;
    a2.x += v2.x; a2.y += v2.y; a2.z += v2.z; a2.w += v2.w;
    a3.x += v3.x; a3.y += v3.y; a3.z += v3.z; a3.w += v3.w;
  }
  for (; s < s1; s += 2) {
    float4 v = base[(size_t)s * HV + t];
    a0.x += v.x; a0.y += v.y; a0.z += v.z; a0.w += v.w;
  }
  const float inv = 1.0f / (float)(s1 - s0);
  float4 r;
  r.x = ((a0.x + a1.x) + (a2.x + a3.x)) * inv;
  r.y = ((a0.y + a1.y) + (a2.y + a3.y)) * inv;
  r.z = ((a0.z + a1.z) + (a2.z + a3.z)) * inv;
  r.w = ((a0.w + a1.w) + (a2.w + a3.w)) * inv;
  reinterpret_cast<float4*>(gp)[((size_t)p * Bn + b) * HV + t] = r;
}

// Launch 2: CRC-half head (R2-exact), chunks c in {2,3} from gp.
__global__ __launch_bounds__(256) void crc_head(
    const float* __restrict__ gp, const float* __restrict__ W1,
    float* __restrict__ P) {
  __shared__ float g[4][384];
  __shared__ float part[2][4][D1];

  const int t = threadIdx.x;
  const int c = 2 + (blockIdx.x & 1);
  const int e0 = (blockIdx.x >> 1) * 4;
  const int dglob0 = c * 384;
  const int dd0 = dglob0 - H;        // 0 or 384

  for (int i = t; i < 384; i += 256) {
    const int e = i / 96;
    const int j = i % 96;
    const float* b0 = gp + (size_t)(e0 + e) * H + dd0;
    float4 u0 = reinterpret_cast<const float4*>(b0)[j];
    float4 u1 = reinterpret_cast<const float4*>(b0 + (size_t)Bn * H)[j];
    float4 v;
    v.x = u0.x + u1.x; v.y = u0.y + u1.y;
    v.z = u0.z + u1.z; v.w = u0.w + u1.w;
    reinterpret_cast<float4*>(&g[e][0])[j] = v;
  }
  __syncthreads();
  head_inner(g, part, W1, P, dglob0, c, e0, t);
}

// Launch 3: combine 4 chunks, relu, dot W2, sigmoid. One wave per example.
__global__ __launch_bounds__(256) void finalize(
    const float* __restrict__ P, const float* __restrict__ b1,
    const float* __restrict__ W2, const float* __restrict__ b2,
    float* __restrict__ out) {
  const int t = threadIdx.x;
  const int w = t >> 6, l = t & 63;
  const int e = blockIdx.x * 4 + w;
  const int k0 = l, k1 = l + 64;
  float h0 = b1[k0], h1 = b1[k1];
  #pragma unroll
  for (int c = 0; c < 4; ++c) {
    h0 += P[((size_t)c * Bn + e) * D1 + k0];
    h1 += P[((size_t)c * Bn + e) * D1 + k1];
  }
  h0 = fmaxf(h0, 0.f); h1 = fmaxf(h1, 0.f);
  float v = h0 * W2[k0] + h1 * W2[k1];
  #pragma unroll
  for (int off = 32; off > 0; off >>= 1) v += __shfl_down(v, off);
  if (l == 0) out[e] = 1.0f / (1.0f + expf(-(v + b2[0])));
}

extern "C" void kernel_launch(void* const* d_in, const int* in_sizes, int n_in,
                              void* d_out, int out_size, void* d_ws, size_t ws_size,
                              hipStream_t stream) {
  const float* feat = (const float*)d_in[0];   // [B,S,H] fp32
  const int* start  = (const int*)d_in[1];     // [B]
  const int* endp   = (const int*)d_in[2];     // [B]
  const float* W1   = (const float*)d_in[3];   // [2H,D1]
  const float* b1   = (const float*)d_in[4];   // [D1]
  const float* W2   = (const float*)d_in[5];   // [D1,1]
  const float* b2   = (const float*)d_in[6];   // [1]
  float* out = (float*)d_out;                  // [B]

  float* wsf = (float*)d_ws;
  float* gp  = wsf;                            // [2][Bn][768]
  float* P   = gp + (size_t)2 * Bn * H;        // [4][Bn][D1]

  hipLaunchKernelGGL(fused_pool_clshead, dim3(NH + Bn * 2), dim3(256), 0,
                     stream, feat, start, endp, gp, W1, P);
  hipLaunchKernelGGL(crc_head, dim3(NH), dim3(256), 0, stream, gp, W1, P);
  hipLaunchKernelGGL(finalize, dim3(Bn / 4), dim3(256), 0, stream,
                     P, b1, W2, b2, out);
}